// Round 3
// baseline (65.220 us; speedup 1.0000x reference)
//
#include <hip/hip_runtime.h>
#include <math.h>

// ANFIS model, collapsed analytically (verified round 1, absmax 9e-13):
//   All MEM_INDEX rows share leading base-3 digit d = r // 2187, and
//   w[j,b] == F0[b]/S for all j (J_LAST=2 -> digit 0). Hence
//     out[b] = F0[b]/S * ( sum_v input[v,b]*Sv[v] + Sv[8] )
//   with Sv[v] = sum_j conseq[9j+v] (j<6561), S = 2187 * sum_b (F0+F1+F2)[b],
//   F_d[b] = 1 / prod_{i=0..7} (1 + (((x_i-c)/a)^2)^bexp)  over rows k=3i+d.
//
// Fused single kernel: 8 blocks x 1024 threads. Every block redundantly
// computes Sv[9] and S (both are global quantities; redundancy is cheaper
// than a second launch + HBM round-trip through d_ws), then block g writes
// output slice [g*256, g*256+256). No workspace used.

#define NB 2048

__device__ __forceinline__ float fast_rcp(float x) { return __builtin_amdgcn_rcpf(x); }
__device__ __forceinline__ float fast_exp2(float x) { return __builtin_amdgcn_exp2f(x); }
__device__ __forceinline__ float fast_log2(float x) { return __builtin_amdgcn_logf(x); }

__global__ __launch_bounds__(1024) void anfis_fused(
    const float* __restrict__ input,     // (8, 2048)
    const float* __restrict__ premise,   // (24, 3) rows [a, b, c]
    const float* __restrict__ conseq,    // (59049,) = 6561 rows of 9
    float* __restrict__ out)             // (2048,)
{
    const int t    = threadIdx.x;
    const int lane = t & 63;
    const int wave = t >> 6;             // 0..15

    __shared__ float s_F0[NB];           // 8 KB: F0 for every batch
    __shared__ float s_svp[16][9];
    __shared__ float s_sp[16];
    __shared__ float s_Sv[9];
    __shared__ float s_invS;

    // ---- Sv[9] partials: conseq as groups of 9 float4 (36 floats = 4 rows),
    //      so the mod-9 bin of each component is static per unrolled slot.
    float sv[9];
    #pragma unroll
    for (int v = 0; v < 9; ++v) sv[v] = 0.0f;
    const float4* c4 = (const float4*)conseq;   // 59049 floats = 1640*36 + 9
    for (int g = t; g < 1640; g += 1024) {
        const float4* base = c4 + g * 9;
        #pragma unroll
        for (int q = 0; q < 9; ++q) {
            float4 f = base[q];
            sv[(4*q + 0) % 9] += f.x;
            sv[(4*q + 1) % 9] += f.y;
            sv[(4*q + 2) % 9] += f.z;
            sv[(4*q + 3) % 9] += f.w;
        }
    }
    if (t == 0) {                        // remainder row (floats 59040..59048)
        #pragma unroll
        for (int v = 0; v < 9; ++v) sv[v] += conseq[59040 + v];
    }

    // ---- premise params (uniform across threads; indices compile-time) ----
    float inva[24], pb2[24], pc[24];
    #pragma unroll
    for (int k = 0; k < 24; ++k) {
        inva[k] = fast_rcp(premise[3*k + 0]);
        pb2[k]  = 2.0f * premise[3*k + 1];   // exponent on |t| is 2*b
        pc[k]   = premise[3*k + 2];
    }

    // ---- memberships for ALL batches (needed for the global S) ----
    float Ssum = 0.0f;
    #pragma unroll
    for (int pass = 0; pass < 2; ++pass) {
        const int b = t + pass * 1024;
        float P0 = 1.0f, P1 = 1.0f, P2 = 1.0f;
        #pragma unroll
        for (int i = 0; i < 8; ++i) {
            const float x = input[i * NB + b];
            #pragma unroll
            for (int d = 0; d < 3; ++d) {
                const int k = 3*i + d;
                const float tt = (x - pc[k]) * inva[k];
                // (((x-c)/a)^2)^b == exp2(2b * log2|t|)
                const float y = fast_exp2(pb2[k] * fast_log2(__builtin_fabsf(tt)));
                const float e = 1.0f + y;
                if (d == 0) P0 *= e; else if (d == 1) P1 *= e; else P2 *= e;
            }
        }
        const float F0 = fast_rcp(P0);
        s_F0[b] = F0;
        Ssum += F0 + fast_rcp(P1) + fast_rcp(P2);
    }

    // ---- block reductions: Sv[9] and Ssum ----
    #pragma unroll
    for (int m = 32; m; m >>= 1) {
        #pragma unroll
        for (int v = 0; v < 9; ++v) sv[v] += __shfl_xor(sv[v], m);
        Ssum += __shfl_xor(Ssum, m);
    }
    if (lane == 0) {
        #pragma unroll
        for (int v = 0; v < 9; ++v) s_svp[wave][v] = sv[v];
        s_sp[wave] = Ssum;
    }
    __syncthreads();
    if (t < 9) {
        float s = 0.0f;
        #pragma unroll
        for (int w2 = 0; w2 < 16; ++w2) s += s_svp[w2][t];
        s_Sv[t] = s;
    }
    if (t == 16) {
        float s = 0.0f;
        #pragma unroll
        for (int w2 = 0; w2 < 16; ++w2) s += s_sp[w2];
        s_invS = 1.0f / (2187.0f * s);   // precise div, executed once
    }
    __syncthreads();

    // ---- output slice for this block ----
    if (t < 256) {
        const int b = blockIdx.x * 256 + t;
        float D = s_Sv[8];
        #pragma unroll
        for (int v = 0; v < 8; ++v) D += input[v * NB + b] * s_Sv[v];
        out[b] = s_F0[b] * D * s_invS;
    }
}

extern "C" void kernel_launch(void* const* d_in, const int* in_sizes, int n_in,
                              void* d_out, int out_size, void* d_ws, size_t ws_size,
                              hipStream_t stream) {
    const float* input   = (const float*)d_in[0];   // 8*2048
    const float* premise = (const float*)d_in[1];   // 24*3
    const float* conseq  = (const float*)d_in[2];   // 59049
    float* out = (float*)d_out;                     // 2048
    (void)d_ws; (void)ws_size;

    anfis_fused<<<8, 1024, 0, stream>>>(input, premise, conseq, out);
}

// Round 4
// 62.601 us; speedup vs baseline: 1.0418x; 1.0418x over previous
//
#include <hip/hip_runtime.h>
#include <math.h>

// ANFIS model, collapsed analytically (verified rounds 1 & 3, absmax 9e-13):
//   All MEM_INDEX rows share leading base-3 digit d = r // 2187, and
//   w[j,b] == F0[b]/S for all j (J_LAST=2 -> digit 0). Hence
//     out[b] = F0[b]/S * ( sum_v input[v,b]*Sv[v] + Sv[8] )
//   with Sv[v] = sum_j conseq[9j+v] (j<6561), S = 2187 * sum_b (F0+F1+F2)[b],
//   F_d[b] = 1 / prod_{i=0..7} (1 + (((x_i-c)/a)^2)^bexp)  over rows k=3i+d.
//
// Two-kernel structure (round-1 best: 62.9 µs vs fused 65.2 µs; the timed
// graph is dominated by the harness's 256 MiB d_ws poison fill ~40 µs, so
// kernel structure deltas are within noise — this is the best-known config)
// with fast hardware transcendentals (v_log_f32/v_exp_f32) replacing powf.

#define NVAR 8
#define TOTALJ 6561
#define NB 2048
#define K1_BLOCKS 64
#define K1_THREADS 256
#define K2_BLOCKS 8
#define K2_THREADS 256

// ws layout (floats):
//   [0,   576)  SvPart[block][9]
//   [576, 640)  SsumPart[block]
//   [640, 2688) F0[b]
#define WS_SV    0
#define WS_SSUM  576
#define WS_F0    640

__device__ __forceinline__ float fast_rcp(float x)  { return __builtin_amdgcn_rcpf(x); }
__device__ __forceinline__ float fast_exp2(float x) { return __builtin_amdgcn_exp2f(x); }
__device__ __forceinline__ float fast_log2(float x) { return __builtin_amdgcn_logf(x); }

__global__ __launch_bounds__(K1_THREADS) void anfis_k1(
    const float* __restrict__ input,     // (8, 2048)
    const float* __restrict__ premise,   // (24, 3) rows [a, b, c]
    const float* __restrict__ conseq,    // (59049,)
    float* __restrict__ ws)
{
    const int t    = threadIdx.x;
    const int g    = blockIdx.x;
    const int gt   = g * K1_THREADS + t;
    const int wave = t >> 6;
    const int lane = t & 63;

    // ---- Part A: Sv partial sums (one conseq row of 9 per thread) ----
    float sv[9];
    #pragma unroll
    for (int v = 0; v < 9; ++v) sv[v] = 0.0f;
    if (gt < TOTALJ) {
        const float* row = conseq + gt * 9;
        #pragma unroll
        for (int v = 0; v < 9; ++v) sv[v] = row[v];
    }
    #pragma unroll
    for (int v = 0; v < 9; ++v) {
        #pragma unroll
        for (int m = 32; m; m >>= 1) sv[v] += __shfl_xor(sv[v], m);
    }
    __shared__ float s_sv[4][9];
    if (lane == 0) {
        #pragma unroll
        for (int v = 0; v < 9; ++v) s_sv[wave][v] = sv[v];
    }

    // ---- Part B: membership + F0 per batch (8 lanes per batch) ----
    const int i  = t & 7;          // variable index 0..7
    const int bl = t >> 3;         // local batch 0..31
    const int b  = g * 32 + bl;

    const float x = input[i * NB + b];
    float m3[3];
    #pragma unroll
    for (int d = 0; d < 3; ++d) {
        const int k = 3 * i + d;
        const float pa = premise[k * 3 + 0];
        const float pb = premise[k * 3 + 1];
        const float pc = premise[k * 3 + 2];
        const float tt = (x - pc) * fast_rcp(pa);
        // (tt^2)^b == exp2(2b * log2|tt|); log2(0)=-inf -> exp2(-inf)=0, matches powf
        const float y = fast_exp2(2.0f * pb * fast_log2(__builtin_fabsf(tt)));
        m3[d] = fast_rcp(1.0f + y);
    }
    // product across the 8 lanes of this batch's group (groups are lane-aligned)
    #pragma unroll
    for (int d = 0; d < 3; ++d) {
        m3[d] *= __shfl_xor(m3[d], 1);
        m3[d] *= __shfl_xor(m3[d], 2);
        m3[d] *= __shfl_xor(m3[d], 4);
    }
    if (i == 0) ws[WS_F0 + b] = m3[0];

    float contrib = (i == 0) ? (m3[0] + m3[1] + m3[2]) : 0.0f;
    #pragma unroll
    for (int m = 32; m; m >>= 1) contrib += __shfl_xor(contrib, m);
    __shared__ float s_c[4];
    if (lane == 0) s_c[wave] = contrib;

    __syncthreads();
    if (t < 9) {
        ws[WS_SV + g * 9 + t] = s_sv[0][t] + s_sv[1][t] + s_sv[2][t] + s_sv[3][t];
    }
    if (t == 9) {
        ws[WS_SSUM + g] = s_c[0] + s_c[1] + s_c[2] + s_c[3];
    }
}

__global__ __launch_bounds__(K2_THREADS) void anfis_k2(
    const float* __restrict__ input,
    const float* __restrict__ ws,
    float* __restrict__ out)
{
    __shared__ float s_Sv[9];
    __shared__ float s_invS;
    const int t = threadIdx.x;

    if (t < 9) {
        float s = 0.0f;
        #pragma unroll 8
        for (int g = 0; g < K1_BLOCKS; ++g) s += ws[WS_SV + g * 9 + t];
        s_Sv[t] = s;
    }
    if (t >= 64 && t < 128) {
        float s = ws[WS_SSUM + (t - 64)];
        #pragma unroll
        for (int m = 32; m; m >>= 1) s += __shfl_xor(s, m);
        if (t == 64) s_invS = 1.0f / (2187.0f * s);
    }
    __syncthreads();

    const int b = blockIdx.x * K2_THREADS + t;
    float D = s_Sv[8];
    #pragma unroll
    for (int v = 0; v < 8; ++v) D += input[v * NB + b] * s_Sv[v];
    out[b] = ws[WS_F0 + b] * D * s_invS;
}

extern "C" void kernel_launch(void* const* d_in, const int* in_sizes, int n_in,
                              void* d_out, int out_size, void* d_ws, size_t ws_size,
                              hipStream_t stream) {
    const float* input   = (const float*)d_in[0];   // 8*2048
    const float* premise = (const float*)d_in[1];   // 24*3
    const float* conseq  = (const float*)d_in[2];   // 59049
    float* out = (float*)d_out;                     // 2048
    float* ws  = (float*)d_ws;

    anfis_k1<<<K1_BLOCKS, K1_THREADS, 0, stream>>>(input, premise, conseq, ws);
    anfis_k2<<<K2_BLOCKS, K2_THREADS, 0, stream>>>(input, ws, out);
}